// Round 7
// baseline (353.497 us; speedup 1.0000x reference)
//
#include <hip/hip_runtime.h>
#include <math.h>

#define F_NODES 16384
#define DEG 8
#define E_TOT (F_NODES * DEG)   // 131072
#define B 64
#define H 16
#define LAYERS 10
#define NPW 2                   // nodes per wave per group
#define NPB 8                   // nodes per group (4 waves * NPW)
#define NGRP 2                  // groups per block (register-pipelined)
#define LGRID (F_NODES / (NPB * NGRP))   // 1024 blocks

typedef unsigned short bf16_t;

__device__ __forceinline__ bf16_t f32_to_bf16(float f)
{
    unsigned u = __float_as_uint(f);
    u = (u + 0x7FFFu + ((u >> 16) & 1u)) >> 16;   // round-to-nearest-even
    return (bf16_t)u;
}
__device__ __forceinline__ float bf16_to_f32(bf16_t h)
{
    return __uint_as_float((unsigned)h << 16);
}
// packed-pair unpack: elem0 = bits[15:0], elem1 = bits[31:16]
__device__ __forceinline__ float bfu_lo(unsigned u) { return __uint_as_float(u << 16); }
__device__ __forceinline__ float bfu_hi(unsigned u) { return __uint_as_float(u & 0xFFFF0000u); }

__device__ __forceinline__ float fast_elu(float x)
{
    float e = __builtin_amdgcn_exp2f(x * 1.44269504088896340736f) - 1.0f;
    return x > 0.0f ? x : e;
}

// ---------------------------------------------------------------------------
// Fused prologue (was 3 dispatches): blocks [0,2048) transpose x0 -> x0T16
// bf16; [2048,2560) build inv; [2560,6656) pack W1/W2 to bf16 pairs.
// All outputs disjoint, consumed only by later dispatches.
// ---------------------------------------------------------------------------
__global__ __launch_bounds__(256) void prologue_kernel(
    const float* __restrict__ x0, bf16_t* __restrict__ xT16,
    const int* __restrict__ in_ixs, int* __restrict__ inv,
    const float* __restrict__ W1, const float* __restrict__ W2,
    unsigned* __restrict__ W1b, unsigned* __restrict__ W2b)
{
    const int bid = blockIdx.x;
    if (bid < E_TOT / 64) {
        // ---- transpose tile: (B,E) fp32 -> (E,B) bf16 ----
        __shared__ float tile[64 * 65];
        const int e0 = bid * 64;
        const int c  = threadIdx.x & 63;
        const int r  = threadIdx.x >> 6;
        #pragma unroll
        for (int i = 0; i < 16; ++i) {
            const int b = r + i * 4;
            tile[c * 65 + b] = x0[(size_t)b * E_TOT + e0 + c];
        }
        __syncthreads();
        const int b = threadIdx.x & 63;
        #pragma unroll
        for (int i = 0; i < 16; ++i) {
            const int el = r + i * 4;
            xT16[(size_t)(e0 + el) * B + b] = f32_to_bf16(tile[el * 65 + b]);
        }
    } else if (bid < E_TOT / 64 + E_TOT / 256) {
        // ---- inv[P[k]] = k ----
        const int k = (bid - E_TOT / 64) * 256 + threadIdx.x;
        inv[in_ixs[k]] = k;
    } else {
        // ---- pack weights fp32 -> bf16 pairs ----
        const int i = (bid - E_TOT / 64 - E_TOT / 256) * 256 + threadIdx.x;
        float2 a = ((const float2*)W1)[i];
        W1b[i] = (unsigned)f32_to_bf16(a.x) | ((unsigned)f32_to_bf16(a.y) << 16);
        float2 c = ((const float2*)W2)[i];
        W2b[i] = (unsigned)f32_to_bf16(c.x) | ((unsigned)f32_to_bf16(c.y) << 16);
    }
}

// ---------------------------------------------------------------------------
// One GSNN layer. z is PRE-PERMUTED (z[k] = x[P[k]]): sequential reads;
// permutation applied by dword-packed scatter-stores via inv.
//   MODE 0: first  — gather bf16 x0T16[P[e]],  scatter bf16 z
//   MODE 1: middle — seq bf16 z in,            scatter bf16 z
//   MODE 2: final  — seq bf16 z in,            fp32 (B,E) natural out
// v6: register-pipelined grid-stride — each block processes NGRP node
// groups; group g+1's z/r global loads are issued BEFORE group g's compute,
// so load latency hides under compute and stores drain under the next
// group's work, breaking the launch-lockstep phase structure.
// ---------------------------------------------------------------------------
template <int MODE>
__global__ __launch_bounds__(256, 4) void layer_kernel(
    const bf16_t*  __restrict__ zin,    // (E, B) bf16 pre-permuted
    const bf16_t*  __restrict__ x0T16,  // (E, B) bf16
    const unsigned* __restrict__ W1b,   // (F, H, DEG/2) packed
    const float*   __restrict__ b1,     // (F, H)
    const unsigned* __restrict__ W2b,   // (F, DEG, H/2) packed
    const float*   __restrict__ b2,     // (F, DEG)
    const int*     __restrict__ in_ixs, // (F, DEG) = P
    const int*     __restrict__ inv,    // (E)      = P^-1
    bf16_t* __restrict__ zout,          // (E, B) bf16 pre-permuted
    float*  __restrict__ out)           // (B, E) fp32 final
{
    // wave-private z/r staging bounce: [wave][node][z=0/r=1][lane] = 16 KB
    __shared__ uint4 stage[4][NPW][2][64];

    const int lane = threadIdx.x & 63;
    const int wv   = threadIdx.x >> 6;

    // current / prefetched register tiles (z0,z1,r0,r1)
    uint4 cz0, cz1, cr0, cr1;
    uint4 pz0, pz1, pr0, pr1;

    // ---- load group 0 into current regs ----
    {
        const int f0 = (((int)blockIdx.x * NGRP + 0) * 4 + wv) * NPW;
        const uint4* rsrc = (const uint4*)(x0T16 + (size_t)f0 * DEG * B);
        cr0 = rsrc[lane];
        cr1 = rsrc[64 + lane];
        if (MODE != 0) {
            const uint4* zsrc = (const uint4*)(zin + (size_t)f0 * DEG * B);
            cz0 = zsrc[lane];
            cz1 = zsrc[64 + lane];
        }
    }

    #pragma unroll
    for (int g = 0; g < NGRP; ++g) {
        const int f0 = __builtin_amdgcn_readfirstlane(
            (((int)blockIdx.x * NGRP + g) * 4 + wv) * NPW);

        // ---- prefetch next group's z/r (loads fly under this compute) ----
        if (g + 1 < NGRP) {
            const int fn = (((int)blockIdx.x * NGRP + g + 1) * 4 + wv) * NPW;
            const uint4* rsrc = (const uint4*)(x0T16 + (size_t)fn * DEG * B);
            pr0 = rsrc[lane];
            pr1 = rsrc[64 + lane];
            if (MODE != 0) {
                const uint4* zsrc = (const uint4*)(zin + (size_t)fn * DEG * B);
                pz0 = zsrc[lane];
                pz1 = zsrc[64 + lane];
            }
        }

        // ---- bounce current regs through wave-private LDS ----
        if (MODE != 0) {
            stage[wv][0][0][lane] = cz0;
            stage[wv][1][0][lane] = cz1;
        }
        stage[wv][0][1][lane] = cr0;
        stage[wv][1][1][lane] = cr1;

        // MODE 0: gather inputs (random lines, one-time layer, scalar)
        float g0[NPW][DEG];
        if (MODE == 0) {
            const int* ixp = in_ixs + f0 * DEG;            // s_load
            #pragma unroll
            for (int n = 0; n < NPW; ++n)
                #pragma unroll
                for (int d = 0; d < DEG; ++d)
                    g0[n][d] = bf16_to_f32(
                        x0T16[(size_t)ixp[n * DEG + d] * B + lane]);
        }

        float oacc[NPW][DEG];

        #pragma unroll
        for (int n = 0; n < NPW; ++n) {
            const int f = f0 + n;

            const bf16_t* zb = (const bf16_t*)&stage[wv][n][0][0];
            const bf16_t* rb = (const bf16_t*)&stage[wv][n][1][0];
            float gv[DEG], rv[DEG];
            #pragma unroll
            for (int d = 0; d < DEG; ++d) {
                gv[d] = (MODE == 0) ? g0[n][d]
                                    : bf16_to_f32(zb[d * 64 + lane]);
                rv[d] = bf16_to_f32(rb[d * 64 + lane]);
            }

            // ---- h = elu(g @ W1^T + b1) ----
            const unsigned* w1 = W1b + f * (H * DEG / 2);   // s_load dwords
            const float*   bb1 = b1 + f * H;
            float h[H];
            #pragma unroll
            for (int j = 0; j < H; ++j) {
                float acc = bb1[j];
                #pragma unroll
                for (int dp = 0; dp < DEG / 2; ++dp) {
                    const unsigned u = w1[j * (DEG / 2) + dp];
                    acc = fmaf(bfu_lo(u), gv[2 * dp],     acc);
                    acc = fmaf(bfu_hi(u), gv[2 * dp + 1], acc);
                }
                h[j] = fast_elu(acc);
            }

            // ---- o = h @ W2^T + b2 + residual ----
            const unsigned* w2 = W2b + f * (DEG * H / 2);   // s_load dwords
            const float*   bb2 = b2 + f * DEG;
            #pragma unroll
            for (int d = 0; d < DEG; ++d) {
                float acc = bb2[d];
                #pragma unroll
                for (int jp = 0; jp < H / 2; ++jp) {
                    const unsigned u = w2[d * (H / 2) + jp];
                    acc = fmaf(bfu_lo(u), h[2 * jp],     acc);
                    acc = fmaf(bfu_hi(u), h[2 * jp + 1], acc);
                }
                oacc[n][d] = acc + rv[d];
            }

            if (MODE != 2) {
                // dword-packed scatter: 32 lanes store one dword each
                const int* invp = inv + f * DEG;            // s_load
                int dwc[DEG];
                #pragma unroll
                for (int d = 0; d < DEG; ++d) {
                    int us = (int)f32_to_bf16(oacc[n][d]);  // low 16 bits
                    int pr = __shfl_xor(us, 1);
                    int dw = us | (pr << 16);               // valid on even lanes
                    dwc[d] = __builtin_amdgcn_ds_bpermute(
                        ((2 * lane) & 63) << 2, dw);        // lane i <- lane 2i
                }
                if (lane < 32) {
                    #pragma unroll
                    for (int d = 0; d < DEG; ++d)
                        ((unsigned*)zout)[(size_t)invp[d] * (B / 2) + lane] =
                            (unsigned)dwc[d];
                }
            }
        }

        if (MODE == 2) {
            // group covers 8 nodes = 64 consecutive e; transpose via padded
            // LDS so the fp32 (B,E) store is full 128-B lines.
            __shared__ float outs[64 * 65];                 // [e_local][b]
            __syncthreads();    // protect tile reuse across groups
            #pragma unroll
            for (int n = 0; n < NPW; ++n)
                #pragma unroll
                for (int d = 0; d < DEG; ++d)
                    outs[((wv * NPW + n) * DEG + d) * 65 + lane] = oacc[n][d];
            __syncthreads();

            const int b  = threadIdx.x >> 2;     // 0..63
            const int c  = threadIdx.x & 3;      // 0..3 (16 floats each)
            const int e0 = ((int)blockIdx.x * NGRP + g) * 64;
            float* dst = out + (size_t)b * E_TOT + e0 + c * 16;
            #pragma unroll
            for (int q = 0; q < 4; ++q) {
                float4 v;
                v.x = outs[(c * 16 + q * 4 + 0) * 65 + b];
                v.y = outs[(c * 16 + q * 4 + 1) * 65 + b];
                v.z = outs[(c * 16 + q * 4 + 2) * 65 + b];
                v.w = outs[(c * 16 + q * 4 + 3) * 65 + b];
                ((float4*)dst)[q] = v;
            }
        }

        // ---- rotate pipeline regs ----
        if (g + 1 < NGRP) {
            cr0 = pr0; cr1 = pr1;
            if (MODE != 0) { cz0 = pz0; cz1 = pz1; }
        }
    }
}

extern "C" void kernel_launch(void* const* d_in, const int* in_sizes, int n_in,
                              void* d_out, int out_size, void* d_ws, size_t ws_size,
                              hipStream_t stream)
{
    const float* x0     = (const float*)d_in[0];
    const float* W1     = (const float*)d_in[1];
    const float* b1     = (const float*)d_in[2];
    const float* W2     = (const float*)d_in[3];
    const float* b2     = (const float*)d_in[4];
    const int*   in_ixs = (const int*)d_in[5];
    float* out = (float*)d_out;

    const size_t NEL = (size_t)E_TOT * B;        // 8.39M elements
    bf16_t*   x0T16 = (bf16_t*)d_ws;             // 16 MB
    bf16_t*   zA    = x0T16 + NEL;               // 16 MB
    bf16_t*   zB    = zA + NEL;                  // 16 MB
    int*      inv   = (int*)(zB + NEL);          // 512 KB
    unsigned* W1b   = (unsigned*)(inv + E_TOT);  // 4.2 MB
    unsigned* W2b   = W1b + F_NODES * H * DEG / 2;

    const int pro_grid = E_TOT / 64 + E_TOT / 256
                       + F_NODES * H * DEG / 2 / 256;   // 6656
    prologue_kernel<<<pro_grid, 256, 0, stream>>>(
        x0, x0T16, in_ixs, inv, W1, W2, W1b, W2b);

    layer_kernel<0><<<LGRID, 256, 0, stream>>>(
        nullptr, x0T16, W1b, b1, W2b, b2, in_ixs, inv, zA, nullptr);

    const bf16_t* cur = zA;
    bf16_t* nxt = zB;
    for (int l = 1; l < LAYERS - 1; ++l) {
        layer_kernel<1><<<LGRID, 256, 0, stream>>>(
            cur, x0T16, W1b, b1, W2b, b2, in_ixs, inv, nxt, nullptr);
        cur = nxt;
        nxt = (nxt == zA) ? zB : zA;
    }

    layer_kernel<2><<<LGRID, 256, 0, stream>>>(
        cur, x0T16, W1b, b1, W2b, b2, in_ixs, inv, nullptr, out);
}